// Round 1
// baseline (697.579 us; speedup 1.0000x reference)
//
#include <hip/hip_runtime.h>

#define NN 50000      // nodes
#define NE 800000     // edges
#define NG 512        // graphs
#define HD 128        // hidden
#define EPS 1e-5f

// ---------------------------------------------------------------- CSR build
__global__ __launch_bounds__(256) void k_hist(const int* __restrict__ dstv,
                                              int* __restrict__ deg, int E) {
    int e = blockIdx.x * 256 + threadIdx.x;
    if (e < E) atomicAdd(&deg[dstv[e]], 1);
}

// single-block exclusive scan: deg[0..n) -> row_ptr[0..n], cursor copy
__global__ __launch_bounds__(1024) void k_scan(const int* __restrict__ deg,
                                               int* __restrict__ row_ptr,
                                               int* __restrict__ cursor, int n) {
    __shared__ int sums[1024];
    const int PT = (n + 1023) / 1024;   // elements per thread
    int t = threadIdx.x;
    int base = t * PT;
    int s = 0;
    for (int j = 0; j < PT; ++j) { int i = base + j; if (i < n) s += deg[i]; }
    sums[t] = s;
    __syncthreads();
    // Hillis-Steele inclusive scan over 1024 thread-totals
    for (int off = 1; off < 1024; off <<= 1) {
        int v = (t >= off) ? sums[t - off] : 0;
        __syncthreads();
        sums[t] += v;
        __syncthreads();
    }
    int p = sums[t] - s;   // exclusive prefix for this thread's span
    for (int j = 0; j < PT; ++j) {
        int i = base + j;
        if (i < n) { int d = deg[i]; row_ptr[i] = p; cursor[i] = p; p += d; }
    }
    if (t == 1023) row_ptr[n] = sums[1023];
}

__global__ __launch_bounds__(256) void k_fill(const int* __restrict__ srcv,
                                              const int* __restrict__ dstv,
                                              const float* __restrict__ w,
                                              int* __restrict__ cursor,
                                              int* __restrict__ col,
                                              float* __restrict__ ew, int E) {
    int e = blockIdx.x * 256 + threadIdx.x;
    if (e < E) {
        int d = dstv[e];
        int p = atomicAdd(&cursor[d], 1);
        col[p] = srcv[e];
        ew[p]  = w[e];
    }
}

// ------------------------------------------------- fused LayerNorm + GEMM
// in: h [N][K] fp32 ; W [K][128] ; out: hw [N][128]
// block: 256 threads handles 16 rows; W staged in 64-row k-chunks in LDS.
template <int K>
__global__ __launch_bounds__(256) void k_ln_gemm(const float* __restrict__ hin,
                                                 const float* __restrict__ g,
                                                 const float* __restrict__ b,
                                                 const float* __restrict__ W,
                                                 float* __restrict__ hw) {
    constexpr int SK = K + 4;           // padded LDS stride (banks)
    constexpr int KC = 64;              // k-chunk
    __shared__ float hs[16][SK];
    __shared__ float wl[KC * HD];
    const int t  = threadIdx.x;
    const int r0 = blockIdx.x * 16;

    // ---- load 16 rows (contiguous 16*K floats) as float4
    const float4* src4 = (const float4*)(hin + (size_t)r0 * K);
    constexpr int NV = 16 * K / 4;      // K%4==0 for 100 and 128
    for (int i = t; i < NV; i += 256) {
        float4 v = src4[i];
        int f = i * 4;
        int r = f / K, k = f - r * K;   // k%4==0
        *(float4*)&hs[r][k] = v;
    }
    __syncthreads();

    // ---- LayerNorm: 16 lanes per row
    {
        int row = t >> 4, l = t & 15;
        float s = 0.f, s2 = 0.f;
        for (int k = l; k < K; k += 16) { float v = hs[row][k]; s += v; s2 += v * v; }
        for (int off = 8; off; off >>= 1) { s += __shfl_xor(s, off); s2 += __shfl_xor(s2, off); }
        float mean = s / (float)K;
        float var  = s2 / (float)K - mean * mean;
        float rstd = rsqrtf(var + EPS);
        for (int k = l; k < K; k += 16)
            hs[row][k] = (hs[row][k] - mean) * rstd * g[k] + b[k];
    }
    __syncthreads();

    // ---- GEMM: thread (c, rb) computes 8 rows x 1 col
    const int c  = t & 127;
    const int rb = (t >> 7) * 8;        // 0 or 8
    float acc[8] = {0.f, 0.f, 0.f, 0.f, 0.f, 0.f, 0.f, 0.f};

    for (int kc = 0; kc < K; kc += KC) {
        const int len = (K - kc < KC) ? (K - kc) : KC;
        // stage W[kc..kc+len)[128] into LDS (row-major, stride 128 -> 2-way free)
        const float4* w4 = (const float4*)(W + (size_t)kc * HD);
        int nv = len * HD / 4;
        for (int i = t; i < nv; i += 256) {
            float4 v = w4[i];
            *(float4*)&wl[i * 4] = v;
        }
        __syncthreads();
        for (int k4 = 0; k4 < len; k4 += 4) {
            float4 h4[8];
#pragma unroll
            for (int r = 0; r < 8; ++r) h4[r] = *(const float4*)&hs[rb + r][kc + k4];
#pragma unroll
            for (int j = 0; j < 4; ++j) {
                float w = wl[(k4 + j) * HD + c];
#pragma unroll
                for (int r = 0; r < 8; ++r) acc[r] += ((const float*)&h4[r])[j] * w;
            }
        }
        __syncthreads();
    }
    float* outp = hw + (size_t)r0 * HD + c;
#pragma unroll
    for (int r = 0; r < 8; ++r) outp[(size_t)(rb + r) * HD] = acc[r];
}

// ------------------------------------------------- CSR gather + bias + relu
__global__ __launch_bounds__(256) void k_aggregate(const float* __restrict__ hw,
                                                   const int* __restrict__ row_ptr,
                                                   const int* __restrict__ col,
                                                   const float* __restrict__ ew,
                                                   const float* __restrict__ bias,
                                                   float* __restrict__ hout, int n) {
    const int t    = threadIdx.x;
    const int grp  = t >> 5;            // 8 node-groups per block
    const int lane = t & 31;            // lane holds channels [4*lane..4*lane+3]
    const int node = blockIdx.x * 8 + grp;
    if (node >= n) return;
    const int e0 = row_ptr[node], e1 = row_ptr[node + 1];
    float4 acc = {0.f, 0.f, 0.f, 0.f};
    int e = e0;
    int s_next = 0; float w_next = 0.f;
    if (e < e1) { s_next = col[e]; w_next = ew[e]; }
    while (e < e1) {
        int s = s_next; float w = w_next;
        ++e;
        if (e < e1) { s_next = col[e]; w_next = ew[e]; }   // 1-deep prefetch
        float4 v = *(const float4*)(hw + (size_t)s * HD + lane * 4);
        acc.x += w * v.x; acc.y += w * v.y; acc.z += w * v.z; acc.w += w * v.w;
    }
    float4 bb = *(const float4*)(bias + lane * 4);
    float4 o;
    o.x = fmaxf(acc.x + bb.x, 0.f);
    o.y = fmaxf(acc.y + bb.y, 0.f);
    o.z = fmaxf(acc.z + bb.z, 0.f);
    o.w = fmaxf(acc.w + bb.w, 0.f);
    *(float4*)(hout + (size_t)node * HD + lane * 4) = o;
}

// ------------------------------------------------- pool (mean per graph) + linear
__global__ __launch_bounds__(128) void k_pool(const float* __restrict__ h,
                                              const int* __restrict__ batch,
                                              const float* __restrict__ Wlin,
                                              const float* __restrict__ blin,
                                              float* __restrict__ out, int n) {
    __shared__ float red[2][128];
    const int gph = blockIdx.x;
    const int c   = threadIdx.x;
    // lower_bound(batch, gph) and lower_bound(batch, gph+1) — batch sorted
    int lo = 0, hi = n;
    while (lo < hi) { int mid = (lo + hi) >> 1; if (batch[mid] < gph) lo = mid + 1; else hi = mid; }
    const int start = lo;
    hi = n;
    while (lo < hi) { int mid = (lo + hi) >> 1; if (batch[mid] < gph + 1) lo = mid + 1; else hi = mid; }
    const int end = lo;
    float sum = 0.f;
    for (int i = start; i < end; ++i) sum += h[(size_t)i * HD + c];
    float cnt = (float)(end - start);
    float pooled = sum / fmaxf(cnt, 1.0f);
    red[0][c] = pooled * Wlin[c * 2 + 0];
    red[1][c] = pooled * Wlin[c * 2 + 1];
    __syncthreads();
    for (int off = 64; off; off >>= 1) {
        if (c < off) { red[0][c] += red[0][c + off]; red[1][c] += red[1][c + off]; }
        __syncthreads();
    }
    if (c == 0) {
        out[gph * 2 + 0] = red[0][0] + blin[0];
        out[gph * 2 + 1] = red[1][0] + blin[1];
    }
}

// ---------------------------------------------------------------- launch
extern "C" void kernel_launch(void* const* d_in, const int* in_sizes, int n_in,
                              void* d_out, int out_size, void* d_ws, size_t ws_size,
                              hipStream_t stream) {
    const float* x     = (const float*)d_in[0];
    const int*   ei    = (const int*)d_in[1];     // [2][E]
    const float* ewt   = (const float*)d_in[2];
    const int*   batch = (const int*)d_in[3];
    const float* ln_g0 = (const float*)d_in[4];
    const float* ln_b0 = (const float*)d_in[5];
    const float* ln_g1 = (const float*)d_in[6];
    const float* ln_b1 = (const float*)d_in[7];
    const float* ln_g2 = (const float*)d_in[8];
    const float* ln_b2 = (const float*)d_in[9];
    const float* W0    = (const float*)d_in[10];
    const float* b0    = (const float*)d_in[11];
    const float* W1    = (const float*)d_in[12];
    const float* b1    = (const float*)d_in[13];
    const float* W2    = (const float*)d_in[14];
    const float* b2    = (const float*)d_in[15];
    const float* Wlin  = (const float*)d_in[16];
    const float* blin  = (const float*)d_in[17];
    float* out = (float*)d_out;

    const int* srcv = ei;
    const int* dstv = ei + NE;

    // workspace carve-up (256B aligned)
    char* ws = (char*)d_ws;
    size_t o = 0;
    auto carve = [&](size_t bytes) { void* p = ws + o; o += (bytes + 255) & ~(size_t)255; return p; };
    int*   deg     = (int*)carve(sizeof(int) * NN);
    int*   row_ptr = (int*)carve(sizeof(int) * (NN + 1));
    int*   cursor  = (int*)carve(sizeof(int) * NN);
    int*   col     = (int*)carve(sizeof(int) * NE);
    float* ew2     = (float*)carve(sizeof(float) * NE);
    float* hW      = (float*)carve(sizeof(float) * NN * HD);
    float* hA      = (float*)carve(sizeof(float) * NN * HD);
    float* hB      = (float*)carve(sizeof(float) * NN * HD);
    (void)ws_size; (void)n_in; (void)in_sizes; (void)out_size;

    // CSR by destination
    hipMemsetAsync(deg, 0, sizeof(int) * NN, stream);
    k_hist<<<(NE + 255) / 256, 256, 0, stream>>>(dstv, deg, NE);
    k_scan<<<1, 1024, 0, stream>>>(deg, row_ptr, cursor, NN);
    k_fill<<<(NE + 255) / 256, 256, 0, stream>>>(srcv, dstv, ewt, cursor, col, ew2, NE);

    const int GEMM_GRID = NN / 16;     // 3125
    const int AGG_GRID  = (NN + 7) / 8;

    // layer 0
    k_ln_gemm<100><<<GEMM_GRID, 256, 0, stream>>>(x, ln_g0, ln_b0, W0, hW);
    k_aggregate<<<AGG_GRID, 256, 0, stream>>>(hW, row_ptr, col, ew2, b0, hA, NN);
    // layer 1
    k_ln_gemm<128><<<GEMM_GRID, 256, 0, stream>>>(hA, ln_g1, ln_b1, W1, hW);
    k_aggregate<<<AGG_GRID, 256, 0, stream>>>(hW, row_ptr, col, ew2, b1, hB, NN);
    // layer 2
    k_ln_gemm<128><<<GEMM_GRID, 256, 0, stream>>>(hB, ln_g2, ln_b2, W2, hW);
    k_aggregate<<<AGG_GRID, 256, 0, stream>>>(hW, row_ptr, col, ew2, b2, hA, NN);
    // pool + classifier
    k_pool<<<NG, 128, 0, stream>>>(hA, batch, Wlin, blin, out, NN);
}

// Round 2
// 551.716 us; speedup vs baseline: 1.2644x; 1.2644x over previous
//
#include <hip/hip_runtime.h>

#define NN 50000      // nodes
#define NE 800000     // edges
#define NG 512        // graphs
#define HD 128        // hidden
#define EPS 1e-5f

// ---------------------------------------------------------------- CSR build
__global__ __launch_bounds__(256) void k_hist(const int* __restrict__ dstv,
                                              int* __restrict__ deg, int E) {
    int e = blockIdx.x * 256 + threadIdx.x;
    if (e < E) atomicAdd(&deg[dstv[e]], 1);
}

// single-block exclusive scan: deg[0..n) -> row_ptr[0..n], cursor copy
__global__ __launch_bounds__(1024) void k_scan(const int* __restrict__ deg,
                                               int* __restrict__ row_ptr,
                                               int* __restrict__ cursor, int n) {
    __shared__ int sums[1024];
    const int PT = (n + 1023) / 1024;   // elements per thread
    int t = threadIdx.x;
    int base = t * PT;
    int s = 0;
    for (int j = 0; j < PT; ++j) { int i = base + j; if (i < n) s += deg[i]; }
    sums[t] = s;
    __syncthreads();
    for (int off = 1; off < 1024; off <<= 1) {
        int v = (t >= off) ? sums[t - off] : 0;
        __syncthreads();
        sums[t] += v;
        __syncthreads();
    }
    int p = sums[t] - s;   // exclusive prefix for this thread's span
    for (int j = 0; j < PT; ++j) {
        int i = base + j;
        if (i < n) { int d = deg[i]; row_ptr[i] = p; cursor[i] = p; p += d; }
    }
    if (t == 1023) row_ptr[n] = sums[1023];
}

__global__ __launch_bounds__(256) void k_fill(const int* __restrict__ srcv,
                                              const int* __restrict__ dstv,
                                              const float* __restrict__ w,
                                              int* __restrict__ cursor,
                                              int* __restrict__ col,
                                              float* __restrict__ ew, int E) {
    int e = blockIdx.x * 256 + threadIdx.x;
    if (e < E) {
        int d = dstv[e];
        int p = atomicAdd(&cursor[d], 1);
        col[p] = srcv[e];
        ew[p]  = w[e];
    }
}

// ------------------------------------------------- fused LayerNorm + GEMM
// in: h [N][K] fp32 ; W [K][128] ; out: hw [N][128]
// 64 rows/block; thread tile 4 rows x 8 cols (acc = 32 VGPR, no spill);
// W staged in 64-k chunks (32 KB), h tile 64x(K+4) (34 KB) -> 2 blocks/CU.
template <int K>
__global__ __launch_bounds__(256, 2) void k_ln_gemm(const float* __restrict__ hin,
                                                    const float* __restrict__ g,
                                                    const float* __restrict__ b,
                                                    const float* __restrict__ W,
                                                    float* __restrict__ hw) {
    constexpr int SK   = K + 4;         // row stride: keeps 16B align, 2-way bank alias (free)
    constexpr int ROWS = 64;
    constexpr int KC   = 64;
    __shared__ float hs[ROWS][SK];      // K=128: 33.8 KB
    __shared__ float wl[KC * HD];       // 32 KB
    const int t  = threadIdx.x;
    const int r0 = blockIdx.x * ROWS;

    // ---- stage up to 64 rows (contiguous span), zero-fill past N
    {
        const float4* src4 = (const float4*)(hin + (size_t)r0 * K);
        const int valid_rows = (NN - r0 < ROWS) ? (NN - r0) : ROWS;
        const int maxf = valid_rows * K;          // multiple of 4 (K%4==0)
        constexpr int NV = ROWS * K / 4;
        for (int i = t; i < NV; i += 256) {
            int f = i * 4;
            float4 v = (f < maxf) ? src4[i] : make_float4(0.f, 0.f, 0.f, 0.f);
            int r = f / K, k = f - r * K;         // k%4==0
            *(float4*)&hs[r][k] = v;
        }
    }
    __syncthreads();

    // ---- LayerNorm: 4 lanes per row
    {
        const int row = t >> 2, l = t & 3;
        float s = 0.f, s2 = 0.f;
        for (int k = l; k < K; k += 4) { float v = hs[row][k]; s += v; s2 += v * v; }
        s  += __shfl_xor(s, 1);  s2 += __shfl_xor(s2, 1);
        s  += __shfl_xor(s, 2);  s2 += __shfl_xor(s2, 2);
        const float mean = s / (float)K;
        const float var  = s2 / (float)K - mean * mean;
        const float rstd = rsqrtf(var + EPS);
        for (int k = l; k < K; k += 4)
            hs[row][k] = (hs[row][k] - mean) * rstd * g[k] + b[k];
    }
    __syncthreads();

    // ---- GEMM: thread (tc,tr) computes rows 4*tr..+3, cols 8*tc..+7
    const int tc  = t & 15;
    const int tr  = t >> 4;
    const int c0  = tc * 8;
    const int rr0 = tr * 4;
    alignas(16) float acc[4][8] = {};

    for (int kc = 0; kc < K; kc += KC) {
        const int len = (K - kc < KC) ? (K - kc) : KC;   // 64 or 36 — multiple of 4
        {   // stage W[kc..kc+len)[128] linearly
            const float4* w4 = (const float4*)(W + (size_t)kc * HD);
            const int nv = len * HD / 4;
            for (int i = t; i < nv; i += 256) *(float4*)&wl[i * 4] = w4[i];
        }
        __syncthreads();
        for (int k4 = 0; k4 < len; k4 += 4) {
            float4 h4[4];
#pragma unroll
            for (int i = 0; i < 4; ++i)
                h4[i] = *(const float4*)&hs[rr0 + i][kc + k4];
#pragma unroll
            for (int j = 0; j < 4; ++j) {
                alignas(16) float wv[8];
                *(float4*)&wv[0] = *(const float4*)&wl[(k4 + j) * HD + c0];
                *(float4*)&wv[4] = *(const float4*)&wl[(k4 + j) * HD + c0 + 4];
#pragma unroll
                for (int i = 0; i < 4; ++i) {
                    const float h = ((const float*)&h4[i])[j];
#pragma unroll
                    for (int cc = 0; cc < 8; ++cc)
                        acc[i][cc] = fmaf(h, wv[cc], acc[i][cc]);
                }
            }
        }
        __syncthreads();
    }

#pragma unroll
    for (int i = 0; i < 4; ++i) {
        const int row = r0 + rr0 + i;
        if (row < NN) {
            *(float4*)&hw[(size_t)row * HD + c0]     = *(const float4*)&acc[i][0];
            *(float4*)&hw[(size_t)row * HD + c0 + 4] = *(const float4*)&acc[i][4];
        }
    }
}

// ------------------------------------------------- CSR gather + bias + relu
__global__ __launch_bounds__(256) void k_aggregate(const float* __restrict__ hw,
                                                   const int* __restrict__ row_ptr,
                                                   const int* __restrict__ col,
                                                   const float* __restrict__ ew,
                                                   const float* __restrict__ bias,
                                                   float* __restrict__ hout, int n) {
    const int t    = threadIdx.x;
    const int grp  = t >> 5;            // 8 node-groups per block
    const int lane = t & 31;            // lane holds channels [4*lane..4*lane+3]
    const int node = blockIdx.x * 8 + grp;
    if (node >= n) return;
    const int e0 = row_ptr[node], e1 = row_ptr[node + 1];
    float4 acc = {0.f, 0.f, 0.f, 0.f};
    int e = e0;
    int s_next = 0; float w_next = 0.f;
    if (e < e1) { s_next = col[e]; w_next = ew[e]; }
    while (e < e1) {
        int s = s_next; float w = w_next;
        ++e;
        if (e < e1) { s_next = col[e]; w_next = ew[e]; }   // 1-deep prefetch
        float4 v = *(const float4*)(hw + (size_t)s * HD + lane * 4);
        acc.x += w * v.x; acc.y += w * v.y; acc.z += w * v.z; acc.w += w * v.w;
    }
    float4 bb = *(const float4*)(bias + lane * 4);
    float4 o;
    o.x = fmaxf(acc.x + bb.x, 0.f);
    o.y = fmaxf(acc.y + bb.y, 0.f);
    o.z = fmaxf(acc.z + bb.z, 0.f);
    o.w = fmaxf(acc.w + bb.w, 0.f);
    *(float4*)(hout + (size_t)node * HD + lane * 4) = o;
}

// ------------------------------------------------- pool (mean per graph) + linear
__global__ __launch_bounds__(128) void k_pool(const float* __restrict__ h,
                                              const int* __restrict__ batch,
                                              const float* __restrict__ Wlin,
                                              const float* __restrict__ blin,
                                              float* __restrict__ out, int n) {
    __shared__ float red[2][128];
    const int gph = blockIdx.x;
    const int c   = threadIdx.x;
    int lo = 0, hi = n;
    while (lo < hi) { int mid = (lo + hi) >> 1; if (batch[mid] < gph) lo = mid + 1; else hi = mid; }
    const int start = lo;
    hi = n;
    while (lo < hi) { int mid = (lo + hi) >> 1; if (batch[mid] < gph + 1) lo = mid + 1; else hi = mid; }
    const int end = lo;
    float sum = 0.f;
    for (int i = start; i < end; ++i) sum += h[(size_t)i * HD + c];
    float cnt = (float)(end - start);
    float pooled = sum / fmaxf(cnt, 1.0f);
    red[0][c] = pooled * Wlin[c * 2 + 0];
    red[1][c] = pooled * Wlin[c * 2 + 1];
    __syncthreads();
    for (int off = 64; off; off >>= 1) {
        if (c < off) { red[0][c] += red[0][c + off]; red[1][c] += red[1][c + off]; }
        __syncthreads();
    }
    if (c == 0) {
        out[gph * 2 + 0] = red[0][0] + blin[0];
        out[gph * 2 + 1] = red[1][0] + blin[1];
    }
}

// ---------------------------------------------------------------- launch
extern "C" void kernel_launch(void* const* d_in, const int* in_sizes, int n_in,
                              void* d_out, int out_size, void* d_ws, size_t ws_size,
                              hipStream_t stream) {
    const float* x     = (const float*)d_in[0];
    const int*   ei    = (const int*)d_in[1];     // [2][E]
    const float* ewt   = (const float*)d_in[2];
    const int*   batch = (const int*)d_in[3];
    const float* ln_g0 = (const float*)d_in[4];
    const float* ln_b0 = (const float*)d_in[5];
    const float* ln_g1 = (const float*)d_in[6];
    const float* ln_b1 = (const float*)d_in[7];
    const float* ln_g2 = (const float*)d_in[8];
    const float* ln_b2 = (const float*)d_in[9];
    const float* W0    = (const float*)d_in[10];
    const float* b0    = (const float*)d_in[11];
    const float* W1    = (const float*)d_in[12];
    const float* b1    = (const float*)d_in[13];
    const float* W2    = (const float*)d_in[14];
    const float* b2    = (const float*)d_in[15];
    const float* Wlin  = (const float*)d_in[16];
    const float* blin  = (const float*)d_in[17];
    float* out = (float*)d_out;

    const int* srcv = ei;
    const int* dstv = ei + NE;

    // workspace carve-up (256B aligned)
    char* ws = (char*)d_ws;
    size_t o = 0;
    auto carve = [&](size_t bytes) { void* p = ws + o; o += (bytes + 255) & ~(size_t)255; return p; };
    int*   deg     = (int*)carve(sizeof(int) * NN);
    int*   row_ptr = (int*)carve(sizeof(int) * (NN + 1));
    int*   cursor  = (int*)carve(sizeof(int) * NN);
    int*   col     = (int*)carve(sizeof(int) * NE);
    float* ew2     = (float*)carve(sizeof(float) * NE);
    float* hW      = (float*)carve(sizeof(float) * NN * HD);
    float* hA      = (float*)carve(sizeof(float) * NN * HD);
    float* hB      = (float*)carve(sizeof(float) * NN * HD);
    (void)ws_size; (void)n_in; (void)in_sizes; (void)out_size;

    // CSR by destination
    hipMemsetAsync(deg, 0, sizeof(int) * NN, stream);
    k_hist<<<(NE + 255) / 256, 256, 0, stream>>>(dstv, deg, NE);
    k_scan<<<1, 1024, 0, stream>>>(deg, row_ptr, cursor, NN);
    k_fill<<<(NE + 255) / 256, 256, 0, stream>>>(srcv, dstv, ewt, cursor, col, ew2, NE);

    const int GEMM_GRID = (NN + 63) / 64;   // 782
    const int AGG_GRID  = (NN + 7) / 8;

    // layer 0
    k_ln_gemm<100><<<GEMM_GRID, 256, 0, stream>>>(x, ln_g0, ln_b0, W0, hW);
    k_aggregate<<<AGG_GRID, 256, 0, stream>>>(hW, row_ptr, col, ew2, b0, hA, NN);
    // layer 1
    k_ln_gemm<128><<<GEMM_GRID, 256, 0, stream>>>(hA, ln_g1, ln_b1, W1, hW);
    k_aggregate<<<AGG_GRID, 256, 0, stream>>>(hW, row_ptr, col, ew2, b1, hB, NN);
    // layer 2
    k_ln_gemm<128><<<GEMM_GRID, 256, 0, stream>>>(hB, ln_g2, ln_b2, W2, hW);
    k_aggregate<<<AGG_GRID, 256, 0, stream>>>(hW, row_ptr, col, ew2, b2, hA, NN);
    // pool + classifier
    k_pool<<<NG, 128, 0, stream>>>(hA, batch, Wlin, blin, out, NN);
}

// Round 3
// 438.034 us; speedup vs baseline: 1.5925x; 1.2595x over previous
//
#include <hip/hip_runtime.h>

#define NN 50000      // nodes
#define NE 800000     // edges
#define NG 512        // graphs
#define HD 128        // hidden
#define EPS 1e-5f
#define NB ((NN + 255) / 256)   // 196 scan blocks

// ---------------------------------------------------------------- CSR build
__global__ __launch_bounds__(256) void k_hist(const int* __restrict__ dstv,
                                              int* __restrict__ deg, int E) {
    int e = blockIdx.x * 256 + threadIdx.x;
    if (e < E) atomicAdd(&deg[dstv[e]], 1);
}

// hierarchical scan, stage 1: per-block sums (coalesced)
__global__ __launch_bounds__(256) void k_blksum(const int* __restrict__ deg,
                                                int* __restrict__ bsum) {
    __shared__ int red[4];
    const int i = blockIdx.x * 256 + threadIdx.x;
    int v = (i < NN) ? deg[i] : 0;
#pragma unroll
    for (int off = 32; off; off >>= 1) v += __shfl_down(v, off);
    const int lane = threadIdx.x & 63, w = threadIdx.x >> 6;
    if (lane == 0) red[w] = v;
    __syncthreads();
    if (threadIdx.x == 0) bsum[blockIdx.x] = red[0] + red[1] + red[2] + red[3];
}

// stage 2: exclusive scan of the NB block sums (single small block)
__global__ __launch_bounds__(256) void k_scan_bsum(const int* __restrict__ bsum,
                                                   int* __restrict__ boff) {
    __shared__ int s[256];
    const int t = threadIdx.x;
    const int v = (t < NB) ? bsum[t] : 0;
    s[t] = v;
    __syncthreads();
    for (int off = 1; off < 256; off <<= 1) {
        int u = (t >= off) ? s[t - off] : 0;
        __syncthreads();
        s[t] += u;
        __syncthreads();
    }
    if (t < NB) boff[t] = s[t] - v;   // exclusive prefix
}

// stage 3: block-local exclusive scan + block offset -> row_ptr, cursor
__global__ __launch_bounds__(256) void k_scan_final(const int* __restrict__ deg,
                                                    const int* __restrict__ boff,
                                                    int* __restrict__ row_ptr,
                                                    int* __restrict__ cursor) {
    __shared__ int s[256];
    const int t = threadIdx.x;
    const int i = blockIdx.x * 256 + t;
    const int v = (i < NN) ? deg[i] : 0;
    s[t] = v;
    __syncthreads();
    for (int off = 1; off < 256; off <<= 1) {
        int u = (t >= off) ? s[t - off] : 0;
        __syncthreads();
        s[t] += u;
        __syncthreads();
    }
    const int ex = boff[blockIdx.x] + s[t] - v;
    if (i < NN) { row_ptr[i] = ex; cursor[i] = ex; }
    if (i == NN - 1) row_ptr[NN] = ex + v;
}

__global__ __launch_bounds__(256) void k_fill(const int* __restrict__ srcv,
                                              const int* __restrict__ dstv,
                                              const float* __restrict__ w,
                                              int* __restrict__ cursor,
                                              int* __restrict__ col,
                                              float* __restrict__ ew, int E) {
    int e = blockIdx.x * 256 + threadIdx.x;
    if (e < E) {
        int d = dstv[e];
        int p = atomicAdd(&cursor[d], 1);
        col[p] = srcv[e];
        ew[p]  = w[e];
    }
}

// ------------------------------------------------- fused LayerNorm + GEMM
// in: h [N][K] fp32 ; W [K][128] ; out: hw [N][128]
// 64 rows/block; thread tile 4 rows x 8 cols (acc = 32 VGPR, no spill);
// W staged in 64-k chunks (32 KB), h tile 64x(K+4) (34 KB) -> 2 blocks/CU.
template <int K>
__global__ __launch_bounds__(256, 2) void k_ln_gemm(const float* __restrict__ hin,
                                                    const float* __restrict__ g,
                                                    const float* __restrict__ b,
                                                    const float* __restrict__ W,
                                                    float* __restrict__ hw) {
    constexpr int SK   = K + 4;         // row stride: keeps 16B align, 2-way bank alias (free)
    constexpr int ROWS = 64;
    constexpr int KC   = 64;
    __shared__ float hs[ROWS][SK];      // K=128: 33.8 KB
    __shared__ float wl[KC * HD];       // 32 KB
    const int t  = threadIdx.x;
    const int r0 = blockIdx.x * ROWS;

    // ---- stage up to 64 rows (contiguous span), zero-fill past N
    {
        const float4* src4 = (const float4*)(hin + (size_t)r0 * K);
        const int valid_rows = (NN - r0 < ROWS) ? (NN - r0) : ROWS;
        const int maxf = valid_rows * K;          // multiple of 4 (K%4==0)
        constexpr int NV = ROWS * K / 4;
        for (int i = t; i < NV; i += 256) {
            int f = i * 4;
            float4 v = (f < maxf) ? src4[i] : make_float4(0.f, 0.f, 0.f, 0.f);
            int r = f / K, k = f - r * K;         // k%4==0
            *(float4*)&hs[r][k] = v;
        }
    }
    __syncthreads();

    // ---- LayerNorm: 4 lanes per row
    {
        const int row = t >> 2, l = t & 3;
        float s = 0.f, s2 = 0.f;
        for (int k = l; k < K; k += 4) { float v = hs[row][k]; s += v; s2 += v * v; }
        s  += __shfl_xor(s, 1);  s2 += __shfl_xor(s2, 1);
        s  += __shfl_xor(s, 2);  s2 += __shfl_xor(s2, 2);
        const float mean = s / (float)K;
        const float var  = s2 / (float)K - mean * mean;
        const float rstd = rsqrtf(var + EPS);
        for (int k = l; k < K; k += 4)
            hs[row][k] = (hs[row][k] - mean) * rstd * g[k] + b[k];
    }
    __syncthreads();

    // ---- GEMM: thread (tc,tr) computes rows 4*tr..+3, cols 8*tc..+7
    const int tc  = t & 15;
    const int tr  = t >> 4;
    const int c0  = tc * 8;
    const int rr0 = tr * 4;
    alignas(16) float acc[4][8] = {};

    for (int kc = 0; kc < K; kc += KC) {
        const int len = (K - kc < KC) ? (K - kc) : KC;   // 64 or 36 — multiple of 4
        {   // stage W[kc..kc+len)[128] linearly
            const float4* w4 = (const float4*)(W + (size_t)kc * HD);
            const int nv = len * HD / 4;
            for (int i = t; i < nv; i += 256) *(float4*)&wl[i * 4] = w4[i];
        }
        __syncthreads();
        for (int k4 = 0; k4 < len; k4 += 4) {
            float4 h4[4];
#pragma unroll
            for (int i = 0; i < 4; ++i)
                h4[i] = *(const float4*)&hs[rr0 + i][kc + k4];
#pragma unroll
            for (int j = 0; j < 4; ++j) {
                alignas(16) float wv[8];
                *(float4*)&wv[0] = *(const float4*)&wl[(k4 + j) * HD + c0];
                *(float4*)&wv[4] = *(const float4*)&wl[(k4 + j) * HD + c0 + 4];
#pragma unroll
                for (int i = 0; i < 4; ++i) {
                    const float h = ((const float*)&h4[i])[j];
#pragma unroll
                    for (int cc = 0; cc < 8; ++cc)
                        acc[i][cc] = fmaf(h, wv[cc], acc[i][cc]);
                }
            }
        }
        __syncthreads();
    }

#pragma unroll
    for (int i = 0; i < 4; ++i) {
        const int row = r0 + rr0 + i;
        if (row < NN) {
            *(float4*)&hw[(size_t)row * HD + c0]     = *(const float4*)&acc[i][0];
            *(float4*)&hw[(size_t)row * HD + c0 + 4] = *(const float4*)&acc[i][4];
        }
    }
}

// ------------------------------------------------- CSR gather + bias + relu
__global__ __launch_bounds__(256) void k_aggregate(const float* __restrict__ hw,
                                                   const int* __restrict__ row_ptr,
                                                   const int* __restrict__ col,
                                                   const float* __restrict__ ew,
                                                   const float* __restrict__ bias,
                                                   float* __restrict__ hout, int n) {
    const int t    = threadIdx.x;
    const int grp  = t >> 5;            // 8 node-groups per block
    const int lane = t & 31;            // lane holds channels [4*lane..4*lane+3]
    const int node = blockIdx.x * 8 + grp;
    if (node >= n) return;
    const int e0 = row_ptr[node], e1 = row_ptr[node + 1];
    float4 acc = {0.f, 0.f, 0.f, 0.f};
    int e = e0;
    int s_next = 0; float w_next = 0.f;
    if (e < e1) { s_next = col[e]; w_next = ew[e]; }
    while (e < e1) {
        int s = s_next; float w = w_next;
        ++e;
        if (e < e1) { s_next = col[e]; w_next = ew[e]; }   // 1-deep prefetch
        float4 v = *(const float4*)(hw + (size_t)s * HD + lane * 4);
        acc.x += w * v.x; acc.y += w * v.y; acc.z += w * v.z; acc.w += w * v.w;
    }
    float4 bb = *(const float4*)(bias + lane * 4);
    float4 o;
    o.x = fmaxf(acc.x + bb.x, 0.f);
    o.y = fmaxf(acc.y + bb.y, 0.f);
    o.z = fmaxf(acc.z + bb.z, 0.f);
    o.w = fmaxf(acc.w + bb.w, 0.f);
    *(float4*)(hout + (size_t)node * HD + lane * 4) = o;
}

// ------------------------------------------------- pool (mean per graph) + linear
__global__ __launch_bounds__(128) void k_pool(const float* __restrict__ h,
                                              const int* __restrict__ batch,
                                              const float* __restrict__ Wlin,
                                              const float* __restrict__ blin,
                                              float* __restrict__ out, int n) {
    __shared__ float red[2][128];
    const int gph = blockIdx.x;
    const int c   = threadIdx.x;
    int lo = 0, hi = n;
    while (lo < hi) { int mid = (lo + hi) >> 1; if (batch[mid] < gph) lo = mid + 1; else hi = mid; }
    const int start = lo;
    hi = n;
    while (lo < hi) { int mid = (lo + hi) >> 1; if (batch[mid] < gph + 1) lo = mid + 1; else hi = mid; }
    const int end = lo;
    float sum = 0.f;
    for (int i = start; i < end; ++i) sum += h[(size_t)i * HD + c];
    float cnt = (float)(end - start);
    float pooled = sum / fmaxf(cnt, 1.0f);
    red[0][c] = pooled * Wlin[c * 2 + 0];
    red[1][c] = pooled * Wlin[c * 2 + 1];
    __syncthreads();
    for (int off = 64; off; off >>= 1) {
        if (c < off) { red[0][c] += red[0][c + off]; red[1][c] += red[1][c + off]; }
        __syncthreads();
    }
    if (c == 0) {
        out[gph * 2 + 0] = red[0][0] + blin[0];
        out[gph * 2 + 1] = red[1][0] + blin[1];
    }
}

// ---------------------------------------------------------------- launch
extern "C" void kernel_launch(void* const* d_in, const int* in_sizes, int n_in,
                              void* d_out, int out_size, void* d_ws, size_t ws_size,
                              hipStream_t stream) {
    const float* x     = (const float*)d_in[0];
    const int*   ei    = (const int*)d_in[1];     // [2][E]
    const float* ewt   = (const float*)d_in[2];
    const int*   batch = (const int*)d_in[3];
    const float* ln_g0 = (const float*)d_in[4];
    const float* ln_b0 = (const float*)d_in[5];
    const float* ln_g1 = (const float*)d_in[6];
    const float* ln_b1 = (const float*)d_in[7];
    const float* ln_g2 = (const float*)d_in[8];
    const float* ln_b2 = (const float*)d_in[9];
    const float* W0    = (const float*)d_in[10];
    const float* b0    = (const float*)d_in[11];
    const float* W1    = (const float*)d_in[12];
    const float* b1    = (const float*)d_in[13];
    const float* W2    = (const float*)d_in[14];
    const float* b2    = (const float*)d_in[15];
    const float* Wlin  = (const float*)d_in[16];
    const float* blin  = (const float*)d_in[17];
    float* out = (float*)d_out;

    const int* srcv = ei;
    const int* dstv = ei + NE;

    // workspace carve-up (256B aligned)
    char* ws = (char*)d_ws;
    size_t o = 0;
    auto carve = [&](size_t bytes) { void* p = ws + o; o += (bytes + 255) & ~(size_t)255; return p; };
    int*   deg     = (int*)carve(sizeof(int) * NN);
    int*   row_ptr = (int*)carve(sizeof(int) * (NN + 1));
    int*   cursor  = (int*)carve(sizeof(int) * NN);
    int*   bsum    = (int*)carve(sizeof(int) * NB);
    int*   boff    = (int*)carve(sizeof(int) * NB);
    int*   col     = (int*)carve(sizeof(int) * NE);
    float* ew2     = (float*)carve(sizeof(float) * NE);
    float* hW      = (float*)carve(sizeof(float) * NN * HD);
    float* hA      = (float*)carve(sizeof(float) * NN * HD);
    float* hB      = (float*)carve(sizeof(float) * NN * HD);
    (void)ws_size; (void)n_in; (void)in_sizes; (void)out_size;

    // CSR by destination (hierarchical scan, all coalesced)
    hipMemsetAsync(deg, 0, sizeof(int) * NN, stream);
    k_hist<<<(NE + 255) / 256, 256, 0, stream>>>(dstv, deg, NE);
    k_blksum<<<NB, 256, 0, stream>>>(deg, bsum);
    k_scan_bsum<<<1, 256, 0, stream>>>(bsum, boff);
    k_scan_final<<<NB, 256, 0, stream>>>(deg, boff, row_ptr, cursor);
    k_fill<<<(NE + 255) / 256, 256, 0, stream>>>(srcv, dstv, ewt, cursor, col, ew2, NE);

    const int GEMM_GRID = (NN + 63) / 64;   // 782
    const int AGG_GRID  = (NN + 7) / 8;

    // layer 0
    k_ln_gemm<100><<<GEMM_GRID, 256, 0, stream>>>(x, ln_g0, ln_b0, W0, hW);
    k_aggregate<<<AGG_GRID, 256, 0, stream>>>(hW, row_ptr, col, ew2, b0, hA, NN);
    // layer 1
    k_ln_gemm<128><<<GEMM_GRID, 256, 0, stream>>>(hA, ln_g1, ln_b1, W1, hW);
    k_aggregate<<<AGG_GRID, 256, 0, stream>>>(hW, row_ptr, col, ew2, b1, hB, NN);
    // layer 2
    k_ln_gemm<128><<<GEMM_GRID, 256, 0, stream>>>(hB, ln_g2, ln_b2, W2, hW);
    k_aggregate<<<AGG_GRID, 256, 0, stream>>>(hW, row_ptr, col, ew2, b2, hA, NN);
    // pool + classifier
    k_pool<<<NG, 128, 0, stream>>>(hA, batch, Wlin, blin, out, NN);
}